// Round 10
// baseline (91.164 us; speedup 1.0000x reference)
//
#include <hip/hip_runtime.h>
#include <stdint.h>

// Problem constants (from reference setup_inputs)
#define BB    8
#define NN    16384
#define KK    1024
#define KNN   16
#define QTR   (NN / 4)      // each of 4 waves per block owns a quarter of points
#define QGRP  (QTR / 4)     // 4-pt load-groups per quarter = 1024
#define NG64  256           // 64-pt lane-groups per batch (4 waves x 64 lanes)
#define GCAP  48            // admitted 64-pt groups per center (expected ~16)
#define SCAP  192           // survivor points per center (expected ~20; <=256 exact bound)

typedef unsigned long long u64;
typedef float f32x2 __attribute__((ext_vector_type(2)));

// ---- packed fp32 ops (VOP3P): lo/hi slots are independent IEEE ops, ----
// ---- bit-identical per slot to the scalar versions (op_sel_hi default). ----
// NOTE: VOP3P f32 is issue-rate-NEUTRAL vs 2 scalar ops on gfx950 (157 TF
// fp32 peak = scalar rate); pk wins are inst-count/latency only.
__device__ __forceinline__ f32x2 pk_fma(f32x2 a, f32x2 b, f32x2 c) {
    f32x2 d;
    asm("v_pk_fma_f32 %0, %1, %2, %3" : "=v"(d) : "v"(a), "v"(b), "v"(c));
    return d;
}
__device__ __forceinline__ f32x2 pk_mul(f32x2 a, f32x2 b) {
    f32x2 d;
    asm("v_pk_mul_f32 %0, %1, %2" : "=v"(d) : "v"(a), "v"(b));
    return d;
}
__device__ __forceinline__ f32x2 pk_add(f32x2 a, f32x2 b) {
    f32x2 d;
    asm("v_pk_add_f32 %0, %1, %2" : "=v"(d) : "v"(a), "v"(b));
    return d;
}
// 3-input float min (exact; min is order-independent for non-NaN values,
// and d' here is always finite).
__device__ __forceinline__ float min3f(float a, float b, float c) {
    float d;
    asm("v_min3_f32 %0, %1, %2, %3" : "=v"(d) : "v"(a), "v"(b), "v"(c));
    return d;
}

// Manual 64-bit shuffle-xor (two 32-bit shuffles).
__device__ __forceinline__ u64 shfl_xor_u64(u64 v, int mask) {
    int lo = (int)(uint32_t)v;
    int hi = (int)(uint32_t)(v >> 32);
    lo = __shfl_xor(lo, mask, 64);
    hi = __shfl_xor(hi, mask, 64);
    return ((u64)(uint32_t)hi << 32) | (u64)(uint32_t)lo;
}

// 64-bit shuffle from a dynamic source lane.
__device__ __forceinline__ u64 shfl_u64(u64 v, int src) {
    int lo = __shfl((int)(uint32_t)v, src, 64);
    int hi = __shfl((int)(uint32_t)(v >> 32), src, 64);
    return ((u64)(uint32_t)hi << 32) | (u64)(uint32_t)lo;
}

// Butterfly min over all 64 lanes; every lane ends with the wave minimum.
__device__ __forceinline__ u64 wave_min_u64(u64 v) {
#pragma unroll
    for (int off = 32; off > 0; off >>= 1) {
        u64 o = shfl_xor_u64(v, off);
        v = o < v ? o : v;
    }
    return v;
}

// Full 64-lane bitonic sort (ascending) of u64 keys carrying a 32-bit payload.
// Real keys are unique ((dist,idx) with unique idx); only padding (~0ull) can
// collide, and padding lanes have all-padding lists, so payload mixing among
// them is harmless. (Extraction scheme harness-verified R12-R19, absmax=0.)
__device__ __forceinline__ void sort64_kv(u64& key, uint32_t& pay, int lane) {
#pragma unroll
    for (int k = 2; k <= 64; k <<= 1) {
#pragma unroll
        for (int j = k >> 1; j > 0; j >>= 1) {
            u64 okey = shfl_xor_u64(key, j);
            uint32_t opay = (uint32_t)__shfl_xor((int)pay, j, 64);
            bool tmin = ((lane & j) == 0) == ((lane & k) == 0);
            bool osm = okey < key;
            bool take = tmin ? osm : !osm;
            if (take) { key = okey; pay = opay; }
        }
    }
}

// Full 64-lane bitonic sort (ascending) of u64 keys, no payload.
__device__ __forceinline__ void sort64_k(u64& key, int lane) {
#pragma unroll
    for (int k = 2; k <= 64; k <<= 1) {
#pragma unroll
        for (int j = k >> 1; j > 0; j >>= 1) {
            u64 okey = shfl_xor_u64(key, j);
            bool tmin = ((lane & j) == 0) == ((lane & k) == 0);
            bool osm = okey < key;
            bool take = tmin ? osm : !osm;
            if (take) key = okey;
        }
    }
}

// EXACT reference d2 (final ranking + fallback): cross = sequential FMA chain
// (einsum -> dot_general -> BLAS microkernel semantics, verified R3);
// x_sq/c_sq plain non-FMA reduce, elementwise ops left-to-right.
__device__ __forceinline__ float point_d2(const float* xb, int i,
                                          float c0, float c1, float c2, float csq) {
#pragma clang fp contract(off)
    float x0 = xb[i * 3 + 0];
    float x1 = xb[i * 3 + 1];
    float x2 = xb[i * 3 + 2];
    float xsq = (x0 * x0 + x1 * x1) + x2 * x2;
    float cross = __fmaf_rn(x2, c2, __fmaf_rn(x1, c1, x0 * c0));
    float d2 = (xsq + csq) - 2.0f * cross;
    return d2 < 0.0f ? 0.0f : d2;   // jnp.maximum(d2, 0)
}

// Cold-path exact fallback (full-N bubble scan), only on cap overflow.
__device__ __attribute__((noinline)) int fallback_scan(const float* xb,
                                                       float c0, float c1, float c2,
                                                       float csq, int lane) {
    u64 list[KNN];
#pragma unroll
    for (int j = 0; j < KNN; ++j) list[j] = ~0ull;
    for (int i = lane; i < NN; i += 64) {
        float d2 = point_d2(xb, i, c0, c1, c2, csq);
        float dist = __fsqrt_rn(d2);
        u64 key = ((u64)__float_as_uint(dist) << 32) | (u64)(uint32_t)i;
        if (key < list[KNN - 1]) {
#pragma unroll
            for (int j = 0; j < KNN; ++j) {
                bool lt = key < list[j];
                u64 lo = lt ? key : list[j];
                u64 hi = lt ? list[j] : key;
                list[j] = lo;
                key = hi;
            }
        }
    }
    int res = 0;
    for (int it = 0; it < KNN; ++it) {
        u64 best = wave_min_u64(list[0]);
        if (it == lane) res = (int)(uint32_t)best;
        if (list[0] == best) {
#pragma unroll
            for (int j = 0; j < KNN - 1; ++j) list[j] = list[j + 1];
            list[KNN - 1] = ~0ull;
        }
    }
    return res;
}

// 16th-smallest FLOAT value of the 64 lane values, via full bitonic sort on
// raw floats (all finite; duplicates fine -- compare-exchange with fmin/fmax
// is a valid sorting network; sorted VALUE multiset identical to the u64
// (sortable-bits,lane) variant -> identical T). Harness-verified R18/R19.
__device__ __forceinline__ float sixteenth_smallest_f(float v, int lane) {
#pragma unroll
    for (int k = 2; k <= 64; k <<= 1) {
#pragma unroll
        for (int j = k >> 1; j > 0; j >>= 1) {
            float o = __shfl_xor(v, j, 64);
            bool takeMin = ((lane & j) == 0) == ((lane & k) == 0);  // k=64: asc
            float mn = fminf(v, o);
            float mx = fmaxf(v, o);
            v = takeMin ? mn : mx;
        }
    }
    return __shfl(v, 15, 64);
}

// Repack 3 raw float4 (one 4-pt AoS group) into six f32x2 pairs + PACKED
// exact xs (per slot (x*x + y*y) + z*z via pk_mul/pk_add -- bit-identical to
// the scalar non-FMA expression; R14-R19-verified).
__device__ __forceinline__ void repack_pairs(float4 f0, float4 f1, float4 f2,
                                             f32x2& xl, f32x2& xh,
                                             f32x2& yl, f32x2& yh,
                                             f32x2& zl, f32x2& zh,
                                             f32x2& sl, f32x2& sh) {
    // p0=(f0.x,f0.y,f0.z) p1=(f0.w,f1.x,f1.y) p2=(f1.z,f1.w,f2.x) p3=(f2.y,f2.z,f2.w)
    xl = f32x2{f0.x, f0.w};  yl = f32x2{f0.y, f1.x};  zl = f32x2{f0.z, f1.y};
    xh = f32x2{f1.z, f2.y};  yh = f32x2{f1.w, f2.z};  zh = f32x2{f2.x, f2.w};
    sl = pk_add(pk_add(pk_mul(xl, xl), pk_mul(yl, yl)), pk_mul(zl, zl));
    sh = pk_add(pk_add(pk_mul(xh, xh), pk_mul(yh, yh)), pk_mul(zh, zh));
}

// R20 (resubmit; round 9 was an infra failure, kernel never ran) = R19 with
// two scan-only issue-efficiency changes:
//  (a) pointer-bump addressing: per-lane float4* advanced by 192/superiter;
//      loads use immediate offsets -> kills per-load v_lshl_add_u64 chains
//      (~6 VALU/group, ~25% of scan instructions);
//  (b) plain `#pragma unroll 4` (16 iters, no remainder, no conditionals --
//      NOT R18's manual prefetch, which spilled; compiler schedules loads
//      within the 64-VGPR budget of __launch_bounds__(256,8)).
// Spill canary: WRITE_SIZE must stay ~1 MB.
// All filter/rank/slack semantics unchanged (absmax=0 chain R12-R19).
__global__ __launch_bounds__(256, 8) void knn_kernel(const float* __restrict__ xyz,
                                                     const float* __restrict__ centers,
                                                     int* __restrict__ out) {
#pragma clang fp contract(off)
    const int q = (int)(threadIdx.x >> 6);    // wave in block = quarter = owned center
    const int lane = (int)(threadIdx.x & 63);
    const int cbase = (int)blockIdx.x * 4;    // global center id of center 0
    const int b = cbase >> 10;                // batch

    __shared__ float    s_min[4][NG64];       // [center][group] 4 KB
    __shared__ uint32_t s_glist[4][GCAP];     // admitted group ids, 768 B
    __shared__ uint32_t s_idx[4][SCAP];       // survivor point ids, 3 KB

    // folded center consts as pk splats: n = -2*c (exact)
    f32x2 nx[4], ny[4], nz[4];
#pragma unroll
    for (int c = 0; c < 4; ++c) {
        float a0 = -2.0f * centers[(cbase + c) * 3 + 0];
        float a1 = -2.0f * centers[(cbase + c) * 3 + 1];
        float a2 = -2.0f * centers[(cbase + c) * 3 + 2];
        nx[c] = f32x2{a0, a0};
        ny[c] = f32x2{a1, a1};
        nz[c] = f32x2{a2, a2};
    }

    const float* xb = xyz + (size_t)b * NN * 3;
    const float4* x4 = (const float4*)xb;     // batch base is 16B-aligned
    const int gbase = q * QGRP;               // first load-group of this quarter

    // ---- Phase A: coalesced scan, lane-group minima in registers ----
    float acc[4];
#pragma unroll
    for (int c = 0; c < 4; ++c) acc[c] = __builtin_inff();
    {
        const float4* p = x4 + (size_t)(gbase + lane) * 3;  // lane's group ptr
#pragma unroll 4
        for (int s = 0; s < QGRP / 64; ++s, p += 192) {  // 16 superiters
            float4 f0 = p[0], f1 = p[1], f2 = p[2];
            f32x2 xl, xh, yl, yh, zl, zh, sl, sh;
            repack_pairs(f0, f1, f2, xl, xh, yl, yh, zl, zh, sl, sh);
#pragma unroll
            for (int c = 0; c < 4; ++c) {
                f32x2 dl = pk_fma(xl, nx[c], pk_fma(yl, ny[c], pk_fma(zl, nz[c], sl)));
                f32x2 dh = pk_fma(xh, nx[c], pk_fma(yh, ny[c], pk_fma(zh, nz[c], sh)));
                acc[c] = min3f(acc[c], dl.x, dl.y);
                acc[c] = min3f(acc[c], dh.x, dh.y);
            }
        }
    }
#pragma unroll
    for (int c = 0; c < 4; ++c) s_min[c][threadIdx.x] = acc[c];
    __syncthreads();                          // the only block barrier

    // ---- Threshold (wave q handles center q; all wave-local below) ----
    float v = fminf(min3f(s_min[q][lane], s_min[q][64 + lane], s_min[q][128 + lane]),
                    s_min[q][192 + lane]);
    float t16 = sixteenth_smallest_f(v, lane);  // >= true 16th-smallest d'
    const float Uq = t16 + fabsf(t16) * 1e-5f + 5e-4f;  // verified slack (R5-R10)
    const u64 ltmask = (1ull << lane) - 1ull;

    // ---- Admit groups by ballot (4 uniform iterations over 256 mins) ----
    int ng = 0;
#pragma unroll
    for (int it = 0; it < NG64 / 64; ++it) {
        int gi = it * 64 + lane;
        bool cnd = s_min[q][gi] <= Uq;
        u64 m = __ballot(cnd);
        int pos = ng + (int)__popcll(m & ltmask);
        if (cnd && pos < GCAP) s_glist[q][pos] = (uint32_t)gi;
        ng += (int)__popcll(m);
    }
    bool ok = (ng <= GCAP);

    // ---- Retest admitted groups: identical pk d', ballot compaction ----
    int total = 0;
    if (ok) {
        const int tasks = ng * 16;            // 16 load-groups per 64-pt group
        const int trips = (tasks + 63) >> 6;
        for (int t = 0; t < trips; ++t) {
            int j = t * 64 + lane;
            bool valid = j < tasks;
            int grp = (int)s_glist[q][valid ? (j >> 4) : 0];
            int ss = j & 15;
            int lg = (grp >> 6) * QGRP + ss * 64 + (grp & 63);  // its load-groups
            float4 f0 = x4[lg * 3 + 0];
            float4 f1 = x4[lg * 3 + 1];
            float4 f2 = x4[lg * 3 + 2];
            f32x2 xl, xh, yl, yh, zl, zh, sl, sh;
            repack_pairs(f0, f1, f2, xl, xh, yl, yh, zl, zh, sl, sh);
            f32x2 dl = pk_fma(xl, nx[q], pk_fma(yl, ny[q], pk_fma(zl, nz[q], sl)));
            f32x2 dh = pk_fma(xh, nx[q], pk_fma(yh, ny[q], pk_fma(zh, nz[q], sh)));
            int ibase = lg * 4;
            bool c0v = valid && (dl.x <= Uq);
            bool c1v = valid && (dl.y <= Uq);
            bool c2v = valid && (dh.x <= Uq);
            bool c3v = valid && (dh.y <= Uq);
            u64 m0 = __ballot(c0v), m1 = __ballot(c1v);
            u64 m2 = __ballot(c2v), m3 = __ballot(c3v);
            int p0 = total + (int)__popcll(m0 & ltmask);
            int b1 = total + (int)__popcll(m0);
            int p1 = b1 + (int)__popcll(m1 & ltmask);
            int b2 = b1 + (int)__popcll(m1);
            int p2 = b2 + (int)__popcll(m2 & ltmask);
            int b3 = b2 + (int)__popcll(m2);
            int p3 = b3 + (int)__popcll(m3 & ltmask);
            if (c0v && p0 < SCAP) s_idx[q][p0] = (uint32_t)(ibase + 0);
            if (c1v && p1 < SCAP) s_idx[q][p1] = (uint32_t)(ibase + 1);
            if (c2v && p2 < SCAP) s_idx[q][p2] = (uint32_t)(ibase + 2);
            if (c3v && p3 < SCAP) s_idx[q][p3] = (uint32_t)(ibase + 3);
            total = b3 + (int)__popcll(m3);
        }
        ok = (total <= SCAP);                 // <= 256 = depth-4 exact bound
    }

    // ---- Rerank center q exactly ----
    const int cc = cbase + q;
    const float c0 = centers[cc * 3 + 0];
    const float c1 = centers[cc * 3 + 1];
    const float c2 = centers[cc * 3 + 2];
    const float csq = (c0 * c0 + c1 * c1) + c2 * c2;  // exact non-FMA reduce

    uint32_t res;
    if (ok) {
        // <=3 keys/lane round-robin -> depth-4 list holds ALL of a lane's
        // keys -> union is the full survivor set (exact).
        u64 l0 = ~0ull, l1 = ~0ull, l2 = ~0ull, l3 = ~0ull;
        for (int j = lane; j < total; j += 64) {
            int idx = (int)s_idx[q][j];
            float d2 = point_d2(xb, idx, c0, c1, c2, csq);
            u64 key = ((u64)__float_as_uint(__fsqrt_rn(d2)) << 32) | (u64)(uint32_t)idx;
            bool tt;
            tt = key < l0; { u64 lo = tt ? key : l0, hi = tt ? l0 : key; l0 = lo; key = hi; }
            tt = key < l1; { u64 lo = tt ? key : l1, hi = tt ? l1 : key; l1 = lo; key = hi; }
            tt = key < l2; { u64 lo = tt ? key : l2, hi = tt ? l2 : key; l2 = lo; key = hi; }
            tt = key < l3; { u64 lo = tt ? key : l3, hi = tt ? l3 : key; l3 = lo; key = hi; }
        }
        if (total <= 64) {
            // Fast path (common: ~20 survivors): each lane holds <=1 real key
            // (round-robin start j=lane), all in l0. One sort ranks them;
            // lanes 0..15 = top-16 (total >= 16 guaranteed: the 16 points
            // achieving the 16 smallest v_L have d' <= T <= Uq).
            sort64_k(l0, lane);
            res = (uint32_t)l0;
        } else {
            // General path (R12-R19-verified): top-16 lie in the 16 lanes
            // with the 16 smallest l0s; gather their 4-lists and sort.
            u64 key = l0;
            uint32_t pay = (uint32_t)lane;
            sort64_kv(key, pay, lane);
            int pos = lane >> 2, elem = lane & 3;
            int sid = __shfl((int)pay, pos, 64);
            u64 g0 = shfl_u64(l0, sid);
            u64 g1 = shfl_u64(l1, sid);
            u64 g2 = shfl_u64(l2, sid);
            u64 g3 = shfl_u64(l3, sid);
            u64 gk = (elem == 0) ? g0 : (elem == 1) ? g1 : (elem == 2) ? g2 : g3;
            sort64_k(gk, lane);
            res = (uint32_t)gk;
        }
    } else {
        res = (uint32_t)fallback_scan(xb, c0, c1, c2, csq, lane);
    }

    // out[b][rank][c_in_batch]
    if (lane < KNN) {
        out[((size_t)b * KNN + lane) * KK + (cc & 1023)] = (int)res;
    }
}

extern "C" void kernel_launch(void* const* d_in, const int* in_sizes, int n_in,
                              void* d_out, int out_size, void* d_ws, size_t ws_size,
                              hipStream_t stream) {
    const float* xyz = (const float*)d_in[0];
    const float* centers = (const float*)d_in[1];
    int* out = (int*)d_out;
    (void)d_ws; (void)ws_size;

    const int nblocks = BB * KK / 4;   // 2048 blocks x 4 waves = 8 blocks/CU, one shot
    hipLaunchKernelGGL(knn_kernel, dim3(nblocks), dim3(256), 0, stream,
                       xyz, centers, out);
}

// Round 11
// 85.203 us; speedup vs baseline: 1.0700x; 1.0700x over previous
//
#include <hip/hip_runtime.h>
#include <stdint.h>

// Problem constants (from reference setup_inputs)
#define BB    8
#define NN    16384
#define KK    1024
#define KNN   16
#define CPB   8             // centers per block (R21: halves per-CU L1 bytes/eval)
#define QTR   (NN / 4)      // each of 4 waves per block owns a quarter of points
#define QGRP  (QTR / 4)     // 4-pt load-groups per quarter = 1024
#define NG64  256           // 64-pt lane-groups per batch (4 waves x 64 lanes)
#define GCAP  48            // admitted 64-pt groups per center (expected ~16)
#define SCAP  192           // survivor points per center (expected ~20; <=256 exact bound)

typedef unsigned long long u64;
typedef float f32x2 __attribute__((ext_vector_type(2)));

// ---- packed fp32 ops (VOP3P): lo/hi slots are independent IEEE ops, ----
// ---- bit-identical per slot to the scalar versions (op_sel_hi default). ----
__device__ __forceinline__ f32x2 pk_fma(f32x2 a, f32x2 b, f32x2 c) {
    f32x2 d;
    asm("v_pk_fma_f32 %0, %1, %2, %3" : "=v"(d) : "v"(a), "v"(b), "v"(c));
    return d;
}
__device__ __forceinline__ f32x2 pk_mul(f32x2 a, f32x2 b) {
    f32x2 d;
    asm("v_pk_mul_f32 %0, %1, %2" : "=v"(d) : "v"(a), "v"(b));
    return d;
}
__device__ __forceinline__ f32x2 pk_add(f32x2 a, f32x2 b) {
    f32x2 d;
    asm("v_pk_add_f32 %0, %1, %2" : "=v"(d) : "v"(a), "v"(b));
    return d;
}
// 3-input float min (exact; min is order-independent for non-NaN values).
__device__ __forceinline__ float min3f(float a, float b, float c) {
    float d;
    asm("v_min3_f32 %0, %1, %2, %3" : "=v"(d) : "v"(a), "v"(b), "v"(c));
    return d;
}

// Manual 64-bit shuffle-xor (two 32-bit shuffles).
__device__ __forceinline__ u64 shfl_xor_u64(u64 v, int mask) {
    int lo = (int)(uint32_t)v;
    int hi = (int)(uint32_t)(v >> 32);
    lo = __shfl_xor(lo, mask, 64);
    hi = __shfl_xor(hi, mask, 64);
    return ((u64)(uint32_t)hi << 32) | (u64)(uint32_t)lo;
}

// 64-bit shuffle from a dynamic source lane.
__device__ __forceinline__ u64 shfl_u64(u64 v, int src) {
    int lo = __shfl((int)(uint32_t)v, src, 64);
    int hi = __shfl((int)(uint32_t)(v >> 32), src, 64);
    return ((u64)(uint32_t)hi << 32) | (u64)(uint32_t)lo;
}

// Butterfly min over all 64 lanes; every lane ends with the wave minimum.
__device__ __forceinline__ u64 wave_min_u64(u64 v) {
#pragma unroll
    for (int off = 32; off > 0; off >>= 1) {
        u64 o = shfl_xor_u64(v, off);
        v = o < v ? o : v;
    }
    return v;
}

// Full 64-lane bitonic sort (ascending) of u64 keys carrying a 32-bit payload.
// (Extraction scheme harness-verified R12-R20, absmax=0.)
__device__ __forceinline__ void sort64_kv(u64& key, uint32_t& pay, int lane) {
#pragma unroll
    for (int k = 2; k <= 64; k <<= 1) {
#pragma unroll
        for (int j = k >> 1; j > 0; j >>= 1) {
            u64 okey = shfl_xor_u64(key, j);
            uint32_t opay = (uint32_t)__shfl_xor((int)pay, j, 64);
            bool tmin = ((lane & j) == 0) == ((lane & k) == 0);
            bool osm = okey < key;
            bool take = tmin ? osm : !osm;
            if (take) { key = okey; pay = opay; }
        }
    }
}

// Full 64-lane bitonic sort (ascending) of u64 keys, no payload.
__device__ __forceinline__ void sort64_k(u64& key, int lane) {
#pragma unroll
    for (int k = 2; k <= 64; k <<= 1) {
#pragma unroll
        for (int j = k >> 1; j > 0; j >>= 1) {
            u64 okey = shfl_xor_u64(key, j);
            bool tmin = ((lane & j) == 0) == ((lane & k) == 0);
            bool osm = okey < key;
            bool take = tmin ? osm : !osm;
            if (take) key = okey;
        }
    }
}

// EXACT reference d2 (final ranking + fallback): cross = sequential FMA chain
// (verified R3); x_sq/c_sq plain non-FMA reduce, elementwise left-to-right.
__device__ __forceinline__ float point_d2(const float* xb, int i,
                                          float c0, float c1, float c2, float csq) {
#pragma clang fp contract(off)
    float x0 = xb[i * 3 + 0];
    float x1 = xb[i * 3 + 1];
    float x2 = xb[i * 3 + 2];
    float xsq = (x0 * x0 + x1 * x1) + x2 * x2;
    float cross = __fmaf_rn(x2, c2, __fmaf_rn(x1, c1, x0 * c0));
    float d2 = (xsq + csq) - 2.0f * cross;
    return d2 < 0.0f ? 0.0f : d2;   // jnp.maximum(d2, 0)
}

// Cold-path exact fallback (full-N bubble scan), only on cap overflow.
__device__ __attribute__((noinline)) int fallback_scan(const float* xb,
                                                       float c0, float c1, float c2,
                                                       float csq, int lane) {
    u64 list[KNN];
#pragma unroll
    for (int j = 0; j < KNN; ++j) list[j] = ~0ull;
    for (int i = lane; i < NN; i += 64) {
        float d2 = point_d2(xb, i, c0, c1, c2, csq);
        float dist = __fsqrt_rn(d2);
        u64 key = ((u64)__float_as_uint(dist) << 32) | (u64)(uint32_t)i;
        if (key < list[KNN - 1]) {
#pragma unroll
            for (int j = 0; j < KNN; ++j) {
                bool lt = key < list[j];
                u64 lo = lt ? key : list[j];
                u64 hi = lt ? list[j] : key;
                list[j] = lo;
                key = hi;
            }
        }
    }
    int res = 0;
    for (int it = 0; it < KNN; ++it) {
        u64 best = wave_min_u64(list[0]);
        if (it == lane) res = (int)(uint32_t)best;
        if (list[0] == best) {
#pragma unroll
            for (int j = 0; j < KNN - 1; ++j) list[j] = list[j + 1];
            list[KNN - 1] = ~0ull;
        }
    }
    return res;
}

// 16th-smallest FLOAT value of the 64 lane values, via full bitonic sort on
// raw floats (valid sorting network; identical T value to u64 variant).
// Harness-verified R18-R20.
__device__ __forceinline__ float sixteenth_smallest_f(float v, int lane) {
#pragma unroll
    for (int k = 2; k <= 64; k <<= 1) {
#pragma unroll
        for (int j = k >> 1; j > 0; j >>= 1) {
            float o = __shfl_xor(v, j, 64);
            bool takeMin = ((lane & j) == 0) == ((lane & k) == 0);  // k=64: asc
            float mn = fminf(v, o);
            float mx = fmaxf(v, o);
            v = takeMin ? mn : mx;
        }
    }
    return __shfl(v, 15, 64);
}

// Repack 3 raw float4 (one 4-pt AoS group) into six f32x2 pairs + PACKED
// exact xs (per slot (x*x + y*y) + z*z via pk_mul/pk_add -- bit-identical to
// the scalar non-FMA expression; R14-R20-verified).
__device__ __forceinline__ void repack_pairs(float4 f0, float4 f1, float4 f2,
                                             f32x2& xl, f32x2& xh,
                                             f32x2& yl, f32x2& yh,
                                             f32x2& zl, f32x2& zh,
                                             f32x2& sl, f32x2& sh) {
    // p0=(f0.x,f0.y,f0.z) p1=(f0.w,f1.x,f1.y) p2=(f1.z,f1.w,f2.x) p3=(f2.y,f2.z,f2.w)
    xl = f32x2{f0.x, f0.w};  yl = f32x2{f0.y, f1.x};  zl = f32x2{f0.z, f1.y};
    xh = f32x2{f1.z, f2.y};  yh = f32x2{f1.w, f2.z};  zh = f32x2{f2.x, f2.w};
    sl = pk_add(pk_add(pk_mul(xl, xl), pk_mul(yl, yl)), pk_mul(zl, zl));
    sh = pk_add(pk_add(pk_mul(xh, xh), pk_mul(yh, yh)), pk_mul(zh, zh));
}

// R21 = R20's lean structure with CPB=8 (the L1-bytes lever):
//  The kernel is L1-throughput-bound, not HBM/VALU-bound: each block streams
//  its batch's full 768 KB through its CU's L1; 2048 blocks = 1.5 GB of L1
//  traffic ~= 38 us at ~64 B/clk/CU -- matching the measured 41 us while
//  VALU-busy is only ~20 us. 8 centers/block halves L1 bytes per pair-eval.
//  - 1024 blocks x 256 thr (4 waves; wave q scans quarter q, same coalesced
//    pointer-bump loads as R20); inner loop evaluates 8 centers per group.
//  - __launch_bounds__(256,4): 16 waves/CU; VGPR headroom for 24 f32x2
//    consts + 8 acc (no spill; WRITE_SIZE is the canary).
//  - Post-scan: wave q serially processes centers 2q, 2q+1 -- per-center
//    code IDENTICAL to R20 (threshold, admit, retest, rerank, fallback);
//    center consts re-loaded scalar per center (no runtime-indexed reg
//    arrays -> no scratch).
// All filter/rank/slack semantics unchanged (absmax=0 chain R12-R20).
__global__ __launch_bounds__(256, 4) void knn_kernel(const float* __restrict__ xyz,
                                                     const float* __restrict__ centers,
                                                     int* __restrict__ out) {
#pragma clang fp contract(off)
    const int q = (int)(threadIdx.x >> 6);    // wave in block = quarter
    const int lane = (int)(threadIdx.x & 63);
    const int cbase = (int)blockIdx.x * CPB;  // global center id of center 0
    const int b = cbase >> 10;                // batch (1024 % 8 == 0)

    __shared__ float    s_min[CPB][NG64];     // [center][group] 8 KB
    __shared__ uint32_t s_glist[CPB][GCAP];   // admitted group ids, 1.5 KB
    __shared__ uint32_t s_idx[CPB][SCAP];     // survivor point ids, 6 KB

    // folded center consts as pk splats: n = -2*c (exact)
    f32x2 nx[CPB], ny[CPB], nz[CPB];
#pragma unroll
    for (int c = 0; c < CPB; ++c) {
        float a0 = -2.0f * centers[(cbase + c) * 3 + 0];
        float a1 = -2.0f * centers[(cbase + c) * 3 + 1];
        float a2 = -2.0f * centers[(cbase + c) * 3 + 2];
        nx[c] = f32x2{a0, a0};
        ny[c] = f32x2{a1, a1};
        nz[c] = f32x2{a2, a2};
    }

    const float* xb = xyz + (size_t)b * NN * 3;
    const float4* x4 = (const float4*)xb;     // batch base is 16B-aligned
    const int gbase = q * QGRP;               // first load-group of this quarter

    // ---- Phase A: coalesced scan, lane-group minima in registers ----
    float acc[CPB];
#pragma unroll
    for (int c = 0; c < CPB; ++c) acc[c] = __builtin_inff();
    {
        const float4* p = x4 + (size_t)(gbase + lane) * 3;  // lane's group ptr
#pragma unroll 2
        for (int s = 0; s < QGRP / 64; ++s, p += 192) {  // 16 superiters
            float4 f0 = p[0], f1 = p[1], f2 = p[2];
            f32x2 xl, xh, yl, yh, zl, zh, sl, sh;
            repack_pairs(f0, f1, f2, xl, xh, yl, yh, zl, zh, sl, sh);
#pragma unroll
            for (int c = 0; c < CPB; ++c) {
                f32x2 dl = pk_fma(xl, nx[c], pk_fma(yl, ny[c], pk_fma(zl, nz[c], sl)));
                f32x2 dh = pk_fma(xh, nx[c], pk_fma(yh, ny[c], pk_fma(zh, nz[c], sh)));
                acc[c] = min3f(acc[c], dl.x, dl.y);
                acc[c] = min3f(acc[c], dh.x, dh.y);
            }
        }
    }
#pragma unroll
    for (int c = 0; c < CPB; ++c) s_min[c][threadIdx.x] = acc[c];
    __syncthreads();                          // the only block barrier

    const u64 ltmask = (1ull << lane) - 1ull;

    // ---- Post-scan: wave q serially handles centers 2q and 2q+1 ----
#pragma unroll
    for (int ci = 0; ci < 2; ++ci) {
        const int c = q * 2 + ci;             // center slot in block
        const int cc = cbase + c;             // global center id

        // Threshold: min over the 4 waves' lane-groups, then 16th-smallest.
        float v = fminf(min3f(s_min[c][lane], s_min[c][64 + lane],
                              s_min[c][128 + lane]),
                        s_min[c][192 + lane]);
        float t16 = sixteenth_smallest_f(v, lane);  // >= true 16th-smallest d'
        const float Uq = t16 + fabsf(t16) * 1e-5f + 5e-4f;  // verified slack

        // Center consts, scalar reload (no runtime-indexed register arrays).
        const float a0 = centers[cc * 3 + 0];
        const float a1 = centers[cc * 3 + 1];
        const float a2 = centers[cc * 3 + 2];
        const f32x2 cnx = f32x2{-2.0f * a0, -2.0f * a0};
        const f32x2 cny = f32x2{-2.0f * a1, -2.0f * a1};
        const f32x2 cnz = f32x2{-2.0f * a2, -2.0f * a2};

        // Admit groups by ballot (4 uniform iterations over 256 mins).
        int ng = 0;
#pragma unroll
        for (int it = 0; it < NG64 / 64; ++it) {
            int gi = it * 64 + lane;
            bool cnd = s_min[c][gi] <= Uq;
            u64 m = __ballot(cnd);
            int pos = ng + (int)__popcll(m & ltmask);
            if (cnd && pos < GCAP) s_glist[c][pos] = (uint32_t)gi;
            ng += (int)__popcll(m);
        }
        bool ok = (ng <= GCAP);

        // Retest admitted groups: identical pk d', ballot compaction.
        int total = 0;
        if (ok) {
            const int tasks = ng * 16;        // 16 load-groups per 64-pt group
            const int trips = (tasks + 63) >> 6;
            for (int t = 0; t < trips; ++t) {
                int j = t * 64 + lane;
                bool valid = j < tasks;
                int grp = (int)s_glist[c][valid ? (j >> 4) : 0];
                int ss = j & 15;
                int lg = (grp >> 6) * QGRP + ss * 64 + (grp & 63);
                float4 f0 = x4[lg * 3 + 0];
                float4 f1 = x4[lg * 3 + 1];
                float4 f2 = x4[lg * 3 + 2];
                f32x2 xl, xh, yl, yh, zl, zh, sl, sh;
                repack_pairs(f0, f1, f2, xl, xh, yl, yh, zl, zh, sl, sh);
                f32x2 dl = pk_fma(xl, cnx, pk_fma(yl, cny, pk_fma(zl, cnz, sl)));
                f32x2 dh = pk_fma(xh, cnx, pk_fma(yh, cny, pk_fma(zh, cnz, sh)));
                int ibase = lg * 4;
                bool c0v = valid && (dl.x <= Uq);
                bool c1v = valid && (dl.y <= Uq);
                bool c2v = valid && (dh.x <= Uq);
                bool c3v = valid && (dh.y <= Uq);
                u64 m0 = __ballot(c0v), m1 = __ballot(c1v);
                u64 m2 = __ballot(c2v), m3 = __ballot(c3v);
                int p0 = total + (int)__popcll(m0 & ltmask);
                int b1 = total + (int)__popcll(m0);
                int p1 = b1 + (int)__popcll(m1 & ltmask);
                int b2 = b1 + (int)__popcll(m1);
                int p2 = b2 + (int)__popcll(m2 & ltmask);
                int b3 = b2 + (int)__popcll(m2);
                int p3 = b3 + (int)__popcll(m3 & ltmask);
                if (c0v && p0 < SCAP) s_idx[c][p0] = (uint32_t)(ibase + 0);
                if (c1v && p1 < SCAP) s_idx[c][p1] = (uint32_t)(ibase + 1);
                if (c2v && p2 < SCAP) s_idx[c][p2] = (uint32_t)(ibase + 2);
                if (c3v && p3 < SCAP) s_idx[c][p3] = (uint32_t)(ibase + 3);
                total = b3 + (int)__popcll(m3);
            }
            ok = (total <= SCAP);             // <= 256 = depth-4 exact bound
        }

        // Rerank center exactly.
        const float csq = (a0 * a0 + a1 * a1) + a2 * a2;  // exact non-FMA
        uint32_t res;
        if (ok) {
            u64 l0 = ~0ull, l1 = ~0ull, l2 = ~0ull, l3 = ~0ull;
            for (int j = lane; j < total; j += 64) {
                int idx = (int)s_idx[c][j];
                float d2 = point_d2(xb, idx, a0, a1, a2, csq);
                u64 key = ((u64)__float_as_uint(__fsqrt_rn(d2)) << 32) | (u64)(uint32_t)idx;
                bool tt;
                tt = key < l0; { u64 lo = tt ? key : l0, hi = tt ? l0 : key; l0 = lo; key = hi; }
                tt = key < l1; { u64 lo = tt ? key : l1, hi = tt ? l1 : key; l1 = lo; key = hi; }
                tt = key < l2; { u64 lo = tt ? key : l2, hi = tt ? l2 : key; l2 = lo; key = hi; }
                tt = key < l3; { u64 lo = tt ? key : l3, hi = tt ? l3 : key; l3 = lo; key = hi; }
            }
            if (total <= 64) {
                // Fast path (common): each lane holds <=1 real key, all in l0.
                sort64_k(l0, lane);
                res = (uint32_t)l0;
            } else {
                // General path (R12-R20-verified).
                u64 key = l0;
                uint32_t pay = (uint32_t)lane;
                sort64_kv(key, pay, lane);
                int pos = lane >> 2, elem = lane & 3;
                int sid = __shfl((int)pay, pos, 64);
                u64 g0 = shfl_u64(l0, sid);
                u64 g1 = shfl_u64(l1, sid);
                u64 g2 = shfl_u64(l2, sid);
                u64 g3 = shfl_u64(l3, sid);
                u64 gk = (elem == 0) ? g0 : (elem == 1) ? g1 : (elem == 2) ? g2 : g3;
                sort64_k(gk, lane);
                res = (uint32_t)gk;
            }
        } else {
            res = (uint32_t)fallback_scan(xb, a0, a1, a2, csq, lane);
        }

        // out[b][rank][c_in_batch]
        if (lane < KNN) {
            out[((size_t)b * KNN + lane) * KK + (cc & 1023)] = (int)res;
        }
    }
}

extern "C" void kernel_launch(void* const* d_in, const int* in_sizes, int n_in,
                              void* d_out, int out_size, void* d_ws, size_t ws_size,
                              hipStream_t stream) {
    const float* xyz = (const float*)d_in[0];
    const float* centers = (const float*)d_in[1];
    int* out = (int*)d_out;
    (void)d_ws; (void)ws_size;

    const int nblocks = BB * KK / CPB;   // 1024 blocks x 4 waves
    hipLaunchKernelGGL(knn_kernel, dim3(nblocks), dim3(256), 0, stream,
                       xyz, centers, out);
}